// Round 2
// baseline (103981.250 us; speedup 1.0000x reference)
//
#include <hip/hip_runtime.h>

// ============================================================================
// Autoregressive 2-layer tanh RNN, B=256, T=512, IN=256, H=1024 (all f32).
//
//   y_t = h1_t @ fc_W^T + fc_b feeds the next step through W_ih0, so
//   y_t @ W_ih0^T = h1_t @ Wc^T + (W_ih0 @ fc_b),  Wc = W_ih0 @ fc_W.
//   Serial chain/step (mode 0): L0 [bar] L1 [bar] fc(no bar, WGs 0..63 only)
//   Fallback (mode 1, small ws): no Wc; read y_{t-1} from d_out; 3 bars/step.
//
// Cooperative launch (residency guaranteed or launch error), grid-stride
// tiles, counter-per-instance grid barrier with agent fences, bounded spin
// with global abort flag (hang -> fast garbage, never a queue timeout).
// ============================================================================

#define B_SZ   256
#define IN_SZ  256
#define H_SZ   1024
#define KC     128
#define KCP    132   // 132%32==4 -> b128 reads hit all banks at data-path rate
#define LTILES 256   // 16 m-blocks(16 rows) x 16 n-blocks(64 cols)
#define FTILES 64    // 16 m-blocks(16 rows) x 4 n-blocks(64 cols)

struct alignas(16) SmemT {
  float A[16][KCP];   // activation rows tile (chunk of K)
  float W[64][KCP];   // weight cols tile (row = output col, along K)
};

struct RnnArgs {
  const float *y0, *W_ih0, *W_hh0, *W_ih1, *W_hh1, *fc_W, *fc_b;
  const float *Wc, *b_init, *b0p, *b1p;
  float *h0a, *h0b, *h1a, *h1b, *out;
  unsigned *cnt, *abortf;
  int T, nwg, mode;
};

// --------------------------------------------------------------------------
// Grid barrier: one counter per instance (memset 0 per launch -> no reset
// race). Bounded spin: on timeout set global abort so ALL WGs drain fast.
// --------------------------------------------------------------------------
__device__ __forceinline__ void grid_barrier(unsigned* cnt, int idx, unsigned nwg,
                                             unsigned* abortf, unsigned* fail_s,
                                             bool* dead) {
  __syncthreads();
  if (*dead) return;
  if (threadIdx.x == 0) {
    __builtin_amdgcn_fence(__ATOMIC_RELEASE, "agent");
    __hip_atomic_fetch_add(&cnt[idx], 1u, __ATOMIC_RELAXED, __HIP_MEMORY_SCOPE_AGENT);
    unsigned f = 0, it = 0;
    while (__hip_atomic_load(&cnt[idx], __ATOMIC_RELAXED, __HIP_MEMORY_SCOPE_AGENT) < nwg) {
      __builtin_amdgcn_s_sleep(2);
      if ((++it & 1023u) == 0u) {
        if (__hip_atomic_load(abortf, __ATOMIC_RELAXED, __HIP_MEMORY_SCOPE_AGENT)) { f = 1; break; }
        if (it > 4000000u) {
          f = 1;
          __hip_atomic_store(abortf, 1u, __ATOMIC_RELAXED, __HIP_MEMORY_SCOPE_AGENT);
          break;
        }
      }
    }
    __builtin_amdgcn_fence(__ATOMIC_ACQUIRE, "agent");
    *fail_s = f;
  }
  __syncthreads();
  if (*fail_s) *dead = true;
}

// --------------------------------------------------------------------------
// acc[j] += sum_k X[m0 + wv + 4j][k] * Wm[n0 + lane][k],  j = 0..3
// X row stride = ldx; Wm row stride = K (contiguous weights).
// --------------------------------------------------------------------------
__device__ __forceinline__ void gemm_accum(const float* __restrict__ X, int ldx,
                                           const float* __restrict__ Wm, int K,
                                           int m0, int n0,
                                           int wv, int lane, int tid,
                                           SmemT& s, float* acc) {
  for (int kc = 0; kc < K; kc += KC) {
    // stage A tile: 16 rows x KC floats = 512 float4; 2 per thread, coalesced
#pragma unroll
    for (int i = 0; i < 2; ++i) {
      int a = i * 256 + tid;
      int r = a >> 5, k = (a & 31) << 2;
      *(float4*)&s.A[r][k] = *(const float4*)&X[(size_t)(m0 + r) * ldx + kc + k];
    }
    // stage W tile: 64 cols x KC floats = 2048 float4; 8 per thread, coalesced
#pragma unroll
    for (int i = 0; i < 8; ++i) {
      int a = i * 256 + tid;
      int c = a >> 5, k = (a & 31) << 2;
      *(float4*)&s.W[c][k] = *(const float4*)&Wm[(size_t)(n0 + c) * K + kc + k];
    }
    __syncthreads();
#pragma unroll 4
    for (int k4 = 0; k4 < KC; k4 += 4) {
      float4 w4 = *(float4*)&s.W[lane][k4];          // per-lane distinct rows
#pragma unroll
      for (int j = 0; j < 4; ++j) {
        float4 a4 = *(float4*)&s.A[wv + 4 * j][k4];  // wave-uniform broadcast
        acc[j] = fmaf(a4.x, w4.x, acc[j]);
        acc[j] = fmaf(a4.y, w4.y, acc[j]);
        acc[j] = fmaf(a4.z, w4.z, acc[j]);
        acc[j] = fmaf(a4.w, w4.w, acc[j]);
      }
    }
    __syncthreads();
  }
}

// --------------------------------------------------------------------------
__global__ void __launch_bounds__(256) rnn_seq_kernel(RnnArgs a) {
  __shared__ SmemT s;
  __shared__ unsigned fail_s;
  bool dead = false;

  const int wg = blockIdx.x, tid = threadIdx.x;
  const int wv = tid >> 6, lane = tid & 63;
  const int T = a.T, nwg = a.nwg, mode = a.mode;
  const int ldo = T * IN_SZ;

  const float* h0[2] = {a.h0a, a.h0b};
  const float* h1[2] = {a.h1a, a.h1b};
  float* h0w[2] = {a.h0a, a.h0b};
  float* h1w[2] = {a.h1a, a.h1b};

  int cur = 0, bar = 0;
  for (int t = 1; t < T; ++t) {
    const int nxt = cur ^ 1;

    // -------- layer 0: h0[nxt] = tanh(input@W^T + h0@W_hh0^T + bias) -------
    for (int tl = wg; tl < LTILES; tl += nwg) {
      const int m0 = (tl >> 4) << 4;
      const int n0 = (((tl & 7) << 1) | ((tl >> 3) & 1)) << 6;  // XCD-local n
      float acc[4] = {0.f, 0.f, 0.f, 0.f};
      const float* bias;
      if (t == 1) {
        gemm_accum(a.y0, IN_SZ, a.W_ih0, IN_SZ, m0, n0, wv, lane, tid, s, acc);
        bias = a.b_init;
      } else if (mode == 0) {
        gemm_accum(h1[cur], H_SZ, a.Wc, H_SZ, m0, n0, wv, lane, tid, s, acc);
        bias = a.b0p;
      } else {
        gemm_accum(a.out + (size_t)(t - 1) * IN_SZ, ldo, a.W_ih0, IN_SZ,
                   m0, n0, wv, lane, tid, s, acc);
        bias = a.b_init;
      }
      gemm_accum(h0[cur], H_SZ, a.W_hh0, H_SZ, m0, n0, wv, lane, tid, s, acc);
      const float bv = bias[n0 + lane];
#pragma unroll
      for (int j = 0; j < 4; ++j)
        h0w[nxt][(size_t)(m0 + wv + 4 * j) * H_SZ + n0 + lane] = tanhf(acc[j] + bv);
    }
    grid_barrier(a.cnt, bar++, (unsigned)nwg, a.abortf, &fail_s, &dead);

    // -------- layer 1: h1[nxt] ---------------------------------------------
    for (int tl = wg; tl < LTILES; tl += nwg) {
      const int m0 = (tl >> 4) << 4;
      const int n0 = (((tl & 7) << 1) | ((tl >> 3) & 1)) << 6;
      float acc[4] = {0.f, 0.f, 0.f, 0.f};
      gemm_accum(h0[nxt], H_SZ, a.W_ih1, H_SZ, m0, n0, wv, lane, tid, s, acc);
      gemm_accum(h1[cur], H_SZ, a.W_hh1, H_SZ, m0, n0, wv, lane, tid, s, acc);
      const float bv = a.b1p[n0 + lane];
#pragma unroll
      for (int j = 0; j < 4; ++j)
        h1w[nxt][(size_t)(m0 + wv + 4 * j) * H_SZ + n0 + lane] = tanhf(acc[j] + bv);
    }
    grid_barrier(a.cnt, bar++, (unsigned)nwg, a.abortf, &fail_s, &dead);

    // -------- fc: y_t (WGs covering 64 tiles; no barrier in mode 0) --------
    for (int ft = wg; ft < FTILES; ft += nwg) {
      const int m0 = (ft >> 2) << 4;
      const int n0 = (ft & 3) << 6;
      float acc[4] = {0.f, 0.f, 0.f, 0.f};
      gemm_accum(h1[nxt], H_SZ, a.fc_W, H_SZ, m0, n0, wv, lane, tid, s, acc);
      const float bv = a.fc_b[n0 + lane];
#pragma unroll
      for (int j = 0; j < 4; ++j)
        a.out[(size_t)(m0 + wv + 4 * j) * ldo + (size_t)t * IN_SZ + n0 + lane] =
            acc[j] + bv;
    }
    if (mode == 1)
      grid_barrier(a.cnt, bar++, (unsigned)nwg, a.abortf, &fail_s, &dead);

    cur = nxt;
  }
}

// --------------------------------------------------------------------------
// Precompute: Wc[i][j] = sum_c W_ih0[i][c] * fc_W[c][j], 1024x1024.
// 262144 float4 outputs; row = 256 float4s  (Round-1 bug: used >>6 / &63,
// scribbling 16MB past Wc -> device fault. Fixed: >>8 / &255.)
// --------------------------------------------------------------------------
__global__ void __launch_bounds__(256) wc_kernel(const float* __restrict__ Wih0,
                                                 const float* __restrict__ fcW,
                                                 float* __restrict__ Wc) {
  int o  = blockIdx.x * 256 + threadIdx.x;
  int i  = o >> 8;               // row 0..1023
  int j0 = (o & 255) << 2;       // col 0..1020
  float4 acc = {0.f, 0.f, 0.f, 0.f};
  for (int c = 0; c < IN_SZ; ++c) {
    float a = Wih0[i * IN_SZ + c];
    float4 f = *(const float4*)&fcW[c * H_SZ + j0];
    acc.x += a * f.x; acc.y += a * f.y; acc.z += a * f.z; acc.w += a * f.w;
  }
  *(float4*)&Wc[(size_t)i * H_SZ + j0] = acc;
}

__global__ void bias_kernel(const float* bih0, const float* bhh0,
                            const float* bih1, const float* bhh1,
                            const float* __restrict__ Wih0,
                            const float* __restrict__ fcb,
                            float* b_init, float* b0p, float* b1p) {
  int i = blockIdx.x * 256 + threadIdx.x;
  if (i < H_SZ) {
    float sum = 0.f;
    for (int c = 0; c < IN_SZ; ++c) sum += Wih0[i * IN_SZ + c] * fcb[c];
    float bi = bih0[i] + bhh0[i];
    b_init[i] = bi;
    b0p[i]    = bi + sum;
    b1p[i]    = bih1[i] + bhh1[i];
  }
}

__global__ void y0copy_kernel(const float* __restrict__ y0,
                              float* __restrict__ out, int T) {
  int o = blockIdx.x * 256 + threadIdx.x;  // 16384 float4: 256 rows x 64 f4
  int b = o >> 6;
  int c = (o & 63) << 2;
  *(float4*)&out[(size_t)b * T * IN_SZ + c] = *(const float4*)&y0[b * IN_SZ + c];
}

// --------------------------------------------------------------------------
extern "C" void kernel_launch(void* const* d_in, const int* in_sizes, int n_in,
                              void* d_out, int out_size, void* d_ws, size_t ws_size,
                              hipStream_t stream) {
  const float* y0    = (const float*)d_in[0];
  const float* W_ih0 = (const float*)d_in[2];
  const float* W_hh0 = (const float*)d_in[3];
  const float* b_ih0 = (const float*)d_in[4];
  const float* b_hh0 = (const float*)d_in[5];
  const float* W_ih1 = (const float*)d_in[6];
  const float* W_hh1 = (const float*)d_in[7];
  const float* b_ih1 = (const float*)d_in[8];
  const float* b_hh1 = (const float*)d_in[9];
  const float* fc_W  = (const float*)d_in[10];
  const float* fc_b  = (const float*)d_in[11];
  const int T = in_sizes[1];  // 512

  // ---- workspace budget & layout (floats) ----
  const size_t hN = (size_t)B_SZ * H_SZ;             // 262144
  const size_t wcN = (size_t)H_SZ * H_SZ;            // 1048576
  const size_t cntN = 3 * (size_t)T + 8;             // counters + abort flag
  const size_t need_full = (wcN + 4 * hN + 3 * H_SZ + cntN) * 4;
  const int mode = (ws_size >= need_full) ? 0 : 1;

  float* ws = (float*)d_ws;
  float* Wc = nullptr;
  if (mode == 0) { Wc = ws; ws += wcN; }
  float* h0a = ws;            ws += hN;
  float* h0b = ws;            ws += hN;
  float* h1a = ws;            ws += hN;
  float* h1b = ws;            ws += hN;
  float* b_init = ws;         ws += H_SZ;
  float* b0p = ws;            ws += H_SZ;
  float* b1p = ws;            ws += H_SZ;
  unsigned* cnt = (unsigned*)ws;
  unsigned* abortf = cnt + 3 * (size_t)T;

  hipMemsetAsync(cnt, 0, cntN * sizeof(unsigned), stream);
  hipMemsetAsync(h0a, 0, hN * sizeof(float), stream);
  hipMemsetAsync(h1a, 0, hN * sizeof(float), stream);

  if (mode == 0)
    wc_kernel<<<(H_SZ * H_SZ / 4) / 256, 256, 0, stream>>>(W_ih0, fc_W, Wc);
  bias_kernel<<<(H_SZ + 255) / 256, 256, 0, stream>>>(
      b_ih0, b_hh0, b_ih1, b_hh1, W_ih0, fc_b, b_init, b0p, b1p);
  y0copy_kernel<<<(B_SZ * IN_SZ / 4) / 256, 256, 0, stream>>>(y0, (float*)d_out, T);

  // ---- co-residency-derived grid + cooperative launch ----
  int nCU = 256;
  hipDeviceGetAttribute(&nCU, hipDeviceAttributeMultiprocessorCount, 0);
  int maxPerCU = 1;
  if (hipOccupancyMaxActiveBlocksPerMultiprocessor(&maxPerCU, rnn_seq_kernel,
                                                   256, 0) != hipSuccess ||
      maxPerCU < 1)
    maxPerCU = 1;
  int nwg = maxPerCU * nCU;
  if (nwg > 256) nwg = 256;
  if (nwg < 8) nwg = 8;

  RnnArgs a;
  a.y0 = y0; a.W_ih0 = W_ih0; a.W_hh0 = W_hh0; a.W_ih1 = W_ih1; a.W_hh1 = W_hh1;
  a.fc_W = fc_W; a.fc_b = fc_b;
  a.Wc = Wc; a.b_init = b_init; a.b0p = b0p; a.b1p = b1p;
  a.h0a = h0a; a.h0b = h0b; a.h1a = h1a; a.h1b = h1b;
  a.out = (float*)d_out; a.cnt = cnt; a.abortf = abortf;
  a.T = T; a.nwg = nwg; a.mode = mode;

  void* kargs[] = {(void*)&a};
  hipError_t err = hipLaunchCooperativeKernel(rnn_seq_kernel, dim3(nwg), dim3(256),
                                              kargs, 0, stream);
  while (err != hipSuccess && nwg > 16) {   // residency fallback: shrink grid
    nwg >>= 1;
    a.nwg = nwg;
    err = hipLaunchCooperativeKernel(rnn_seq_kernel, dim3(nwg), dim3(256),
                                     kargs, 0, stream);
  }
}

// Round 5
// 43282.965 us; speedup vs baseline: 2.4024x; 2.4024x over previous
//
#include <hip/hip_runtime.h>

// ============================================================================
// Autoregressive 2-layer tanh RNN, B=256, T=512, IN=256, H=1024.
//
// Round-5: MFMA path with f32-EXACT h-state (stored f32, round-2-proven
// store pattern) + on-the-fly register split2 (RTZ hi16) of the A operand +
// freshly rewritten weight pack2 layout [row][k/8][plane][8] + 3 products
// (a0b0 + a0b1 + a1b0). Error budget: ra <= 2^-16|a|, rb <= 2^-18|b|,
// missing a1b1 <= 2^-17|ab| -> eps/step ~3e-6 -> final ~3e-3 (threshold 8.4e-2).
//
// Rationale: rounds 3/4 failed with bit-identical absmax 0.41 despite a
// completely different product schedule => defect in the shared split3
// storage chain. This round removes h planes from memory entirely and
// rewrites the weight split fresh.
//
//   y_t @ W_ih0^T = h1_t @ Wc^T + (W_ih0 @ fc_b),  Wc = W_ih0 @ fc_W.
//   step: h0' = tanh(h1@Wc^T + h0@Whh0^T + b0')    [grid bar]
//         h1' = tanh(h0'@Wih1^T + h1@Whh1^T + b1') [grid bar]
//         y_t = h1'@fc_W^T + fc_b                  (write-only, no bar)
//
// 64 persistent WGs x 256 thr (cooperative; completes reliably per r3/r4).
// WG owns a 64x64 tile; 4 waves k-split the 2048-concat (512 each); wave =
// 4x4 frags of 16x16x32 MFMA. LDS only for the 4-way K-reduction.
// ============================================================================

#define B_SZ   256
#define IN_SZ  256
#define H_SZ   1024
#define KCAT   2048
#define NWG_M  64

typedef short v8s __attribute__((ext_vector_type(8)));
typedef float v4f __attribute__((ext_vector_type(4)));

// ---------------- bf16 helpers ----------------
__device__ __forceinline__ unsigned short bf16rne(float f) {
  unsigned x = __builtin_bit_cast(unsigned, f);
  return (unsigned short)((x + 0x7fffu + ((x >> 16) & 1u)) >> 16);
}
__device__ __forceinline__ float bf2f(unsigned short u) {
  unsigned x = ((unsigned)u) << 16;
  return __builtin_bit_cast(float, x);
}

// On-the-fly 2-level RTZ split of 8 consecutive f32 -> two bf16x8 fragments.
// a0 = hi16(v) (RTZ bf16), a1 = hi16(v - a0); residual <= 2^-16 |v|.
__device__ __forceinline__ void split8(const float* __restrict__ p,
                                       v8s& a0, v8s& a1) {
  float4 x0 = *(const float4*)p;
  float4 x1 = *(const float4*)(p + 4);
  float v[8] = {x0.x, x0.y, x0.z, x0.w, x1.x, x1.y, x1.z, x1.w};
  v8s h, l;
#pragma unroll
  for (int j = 0; j < 8; ++j) {
    unsigned u = __builtin_bit_cast(unsigned, v[j]);
    float r = v[j] - __builtin_bit_cast(float, u & 0xFFFF0000u);
    h[j] = (short)(u >> 16);
    l[j] = (short)(__builtin_bit_cast(unsigned, r) >> 16);
  }
  a0 = h; a1 = l;
}

// ---------------- grid barrier (proven r2-r4) ----------------
__device__ __forceinline__ void grid_barrier(unsigned* cnt, int idx, unsigned nwg,
                                             unsigned* abortf, unsigned* fail_s,
                                             bool* dead) {
  __syncthreads();
  if (*dead) return;
  if (threadIdx.x == 0) {
    __builtin_amdgcn_fence(__ATOMIC_RELEASE, "agent");
    __hip_atomic_fetch_add(&cnt[idx], 1u, __ATOMIC_RELAXED, __HIP_MEMORY_SCOPE_AGENT);
    unsigned f = 0, it = 0;
    while (__hip_atomic_load(&cnt[idx], __ATOMIC_RELAXED, __HIP_MEMORY_SCOPE_AGENT) < nwg) {
      __builtin_amdgcn_s_sleep(2);
      if ((++it & 1023u) == 0u) {
        if (__hip_atomic_load(abortf, __ATOMIC_RELAXED, __HIP_MEMORY_SCOPE_AGENT)) { f = 1; break; }
        if (it > 4000000u) {
          f = 1;
          __hip_atomic_store(abortf, 1u, __ATOMIC_RELAXED, __HIP_MEMORY_SCOPE_AGENT);
          break;
        }
      }
    }
    __builtin_amdgcn_fence(__ATOMIC_ACQUIRE, "agent");
    *fail_s = f;
  }
  __syncthreads();
  if (*fail_s) *dead = true;
}

// ============================================================================
// MFMA path
// ============================================================================
struct MArgs {
  const float* y0;
  const unsigned short *B0p, *B1p, *W0p, *fcp;
  float *h0a, *h0b, *h1a, *h1b;
  const float *b_init, *b0p, *b1p, *fc_b;
  float* out;
  unsigned *cnt, *abortf;
  int T, nwg;
};

// acc[fr][fc] += X-slice @ Bp-slice^T over ksteps*32 of K.
// X: f32 [rows][ldx], split2 on the fly. Bp: pack2 layout — for output col n
// and k-block kb (8 k's), 16 shorts at ((n*KBtot + kb)*16): [0..7]=s0, [8..15]=s1.
// 3 products: a0b0 + a0b1 + a1b0.
__device__ __forceinline__ void gemm2f(
    const float* __restrict__ X, int ldx, int am0, int ak0,
    const unsigned short* __restrict__ Bp, int KBtot, int bn0, int bk0,
    int ksteps, int l15, int l4, v4f acc[4][4]) {
  const float* Ab = X + (long)(am0 + l15) * ldx + ak0 + l4 * 8;
  const unsigned short* Bb =
      Bp + ((long)(bn0 + l15) * KBtot + (bk0 >> 3) + l4) * 16;
  for (int ks = 0; ks < ksteps; ++ks) {
    v8s a0[4], a1[4], b0[4], b1[4];
#pragma unroll
    for (int f = 0; f < 4; ++f) {
      split8(Ab + (long)f * 16 * ldx + ks * 32, a0[f], a1[f]);
      const unsigned short* bp = Bb + (long)f * 16 * KBtot * 16 + ks * 64;
      b0[f] = *(const v8s*)bp;
      b1[f] = *(const v8s*)(bp + 8);
    }
#pragma unroll
    for (int fr = 0; fr < 4; ++fr) {
#pragma unroll
      for (int fc = 0; fc < 4; ++fc) {
        v4f c = acc[fr][fc];
        c = __builtin_amdgcn_mfma_f32_16x16x32_bf16(a0[fr], b1[fc], c, 0, 0, 0);
        c = __builtin_amdgcn_mfma_f32_16x16x32_bf16(a1[fr], b0[fc], c, 0, 0, 0);
        c = __builtin_amdgcn_mfma_f32_16x16x32_bf16(a0[fr], b0[fc], c, 0, 0, 0);
        acc[fr][fc] = c;
      }
    }
  }
}

#define RSTRIDE 68

__global__ void __launch_bounds__(256, 1) rnn_mfma_kernel(MArgs a) {
  __shared__ float red[4][64 * RSTRIDE];   // ~69.6 KB
  __shared__ unsigned fail_s;
  bool dead = false;

  const int wg = blockIdx.x, tid = threadIdx.x;
  const int wv = tid >> 6, lane = tid & 63;
  const int l15 = lane & 15, l4 = lane >> 4;
  const int T = a.T, nwg = a.nwg;
  const long ldo = (long)T * IN_SZ;

  const int m0 = (wg >> 4) * 64;   // 4 m-blocks cover B=256
  const int n0 = (wg & 15) * 64;   // 16 n-blocks; same-n sharers co-XCD (wg%8)
  const int fn0 = (wg & 15) * 16;  // fc: 64x16 tile covers IN=256

  float* h0p[2] = {a.h0a, a.h0b};
  float* h1p[2] = {a.h1a, a.h1b};

  v4f zero = {0.f, 0.f, 0.f, 0.f};
  int cur = 0, bar = 0;

  // wave -> K-slice: wv&1 = k-half within operand, wv>>1 = operand segment.
  const int ak0 = 512 * (wv & 1);
  const int bk0 = ak0 + (wv >> 1) * 1024;

  for (int t = 1; t < T; ++t) {
    const int nxt = cur ^ 1;

    // ================= Layer 0: h0[nxt] =================
    {
      v4f acc[4][4];
#pragma unroll
      for (int i = 0; i < 4; ++i)
#pragma unroll
        for (int j = 0; j < 4; ++j) acc[i][j] = zero;

      if (t == 1) {
        // y0 (f32, K=256) @ W_ih0^T; wave k-slice 64
        gemm2f(a.y0, IN_SZ, m0, 64 * wv, a.W0p, 32, n0, 64 * wv,
               2, l15, l4, acc);
      } else {
        const float* X = (wv < 2) ? h1p[cur] : h0p[cur];
        gemm2f(X, H_SZ, m0, ak0, a.B0p, 256, n0, bk0, 16, l15, l4, acc);
      }
      // ---- 4-way K-reduction + bias + tanh + f32 store ----
      float* my = &red[wv][0];
#pragma unroll
      for (int fr = 0; fr < 4; ++fr)
#pragma unroll
        for (int fc = 0; fc < 4; ++fc)
#pragma unroll
          for (int j = 0; j < 4; ++j)
            my[(fr * 16 + l4 * 4 + j) * RSTRIDE + fc * 16 + l15] = acc[fr][fc][j];
      __syncthreads();
      const float* bias = (t == 1) ? a.b_init : a.b0p;
      float* dst = h0p[nxt];
#pragma unroll
      for (int i = 0; i < 16; ++i) {
        int idx = i * 256 + tid;
        int row = idx >> 6, col = idx & 63;
        int ro = row * RSTRIDE + col;
        float v = red[0][ro] + red[1][ro] + red[2][ro] + red[3][ro];
        dst[(long)(m0 + row) * H_SZ + n0 + col] = tanhf(v + bias[n0 + col]);
      }
    }
    grid_barrier(a.cnt, bar++, (unsigned)nwg, a.abortf, &fail_s, &dead);

    // ================= Layer 1: h1[nxt] =================
    {
      v4f acc[4][4];
#pragma unroll
      for (int i = 0; i < 4; ++i)
#pragma unroll
        for (int j = 0; j < 4; ++j) acc[i][j] = zero;

      const float* X = (wv < 2) ? h0p[nxt] : h1p[cur];
      gemm2f(X, H_SZ, m0, ak0, a.B1p, 256, n0, bk0, 16, l15, l4, acc);

      float* my = &red[wv][0];
#pragma unroll
      for (int fr = 0; fr < 4; ++fr)
#pragma unroll
        for (int fc = 0; fc < 4; ++fc)
#pragma unroll
          for (int j = 0; j < 4; ++j)
            my[(fr * 16 + l4 * 4 + j) * RSTRIDE + fc * 16 + l15] = acc[fr][fc][j];
      __syncthreads();
      float* dst = h1p[nxt];
#pragma unroll
      for (int i = 0; i < 16; ++i) {
        int idx = i * 256 + tid;
        int row = idx >> 6, col = idx & 63;
        int ro = row * RSTRIDE + col;
        float v = red[0][ro] + red[1][ro] + red[2][ro] + red[3][ro];
        dst[(long)(m0 + row) * H_SZ + n0 + col] = tanhf(v + a.b1p[n0 + col]);
      }
    }
    grid_barrier(a.cnt, bar++, (unsigned)nwg, a.abortf, &fail_s, &dead);

    // ================= FC: y_t (write-only, no barrier) =================
    {
      // 64 rows x 16 cols; K=1024 split 4x256 across waves; 3 products.
      v4f facc[4] = {zero, zero, zero, zero};
      const float* Ab = h1p[nxt] + (long)(m0 + l15) * H_SZ + 256 * wv + l4 * 8;
      const unsigned short* Bb =
          a.fcp + ((long)(fn0 + l15) * 128 + 32 * wv + l4) * 16;
      for (int ks = 0; ks < 8; ++ks) {
        const unsigned short* bp = Bb + ks * 64;
        v8s b0 = *(const v8s*)bp;
        v8s b1 = *(const v8s*)(bp + 8);
#pragma unroll
        for (int f = 0; f < 4; ++f) {
          v8s a0, a1;
          split8(Ab + (long)f * 16 * H_SZ + ks * 32, a0, a1);
          facc[f] = __builtin_amdgcn_mfma_f32_16x16x32_bf16(a0, b1, facc[f], 0, 0, 0);
          facc[f] = __builtin_amdgcn_mfma_f32_16x16x32_bf16(a1, b0, facc[f], 0, 0, 0);
          facc[f] = __builtin_amdgcn_mfma_f32_16x16x32_bf16(a0, b0, facc[f], 0, 0, 0);
        }
      }
      float* my = &red[wv][0];   // reuse as [64][17]
#pragma unroll
      for (int f = 0; f < 4; ++f)
#pragma unroll
        for (int j = 0; j < 4; ++j)
          my[(f * 16 + l4 * 4 + j) * 17 + l15] = facc[f][j];
      __syncthreads();
#pragma unroll
      for (int i = 0; i < 4; ++i) {
        int idx = i * 256 + tid;
        int row = idx >> 4, col = idx & 15;
        int ro = row * 17 + col;
        float v = red[0][ro] + red[1][ro] + red[2][ro] + red[3][ro] + a.fc_b[fn0 + col];
        a.out[(long)(m0 + row) * ldo + (long)t * IN_SZ + fn0 + col] = v;
      }
      __syncthreads();
    }
    cur = nxt;
  }
}

// ---------------- precompute kernels (fresh pack2 layout) ----------------
// pack2: src f32 [R][CB*8] -> dst records of 16 shorts at (r*KBtot + kboff + cb)
// record = [s0 x8][s1 x8], s0=rne(v), s1=rne(v-s0)  (residual 2^-18 |v|).
__global__ void __launch_bounds__(256) pack2_kernel(
    const float* __restrict__ src, int R, int CB,
    unsigned short* __restrict__ dst, int KBtot, int kboff) {
  int i = blockIdx.x * 256 + threadIdx.x;
  if (i >= R * CB) return;
  int r = i / CB, cb = i - r * CB;
  const float* s = src + (long)r * (CB * 8) + cb * 8;
  unsigned short w[16];
#pragma unroll
  for (int e = 0; e < 8; ++e) {
    float v = s[e];
    unsigned short s0 = bf16rne(v);
    float rr = v - bf2f(s0);
    w[e] = s0;
    w[8 + e] = bf16rne(rr);
  }
  unsigned short* d = dst + ((long)r * KBtot + kboff + cb) * 16;
#pragma unroll
  for (int e = 0; e < 16; ++e) d[e] = w[e];
}

// Wc = W_ih0 @ fc_W packed into B0p k-blocks [0,128)  (KBtot=256).
__global__ void __launch_bounds__(256) wc_pack2_kernel(
    const float* __restrict__ Wih0, const float* __restrict__ fcW,
    unsigned short* __restrict__ dst) {
  int i = blockIdx.x * 256 + threadIdx.x;   // over 1024*128
  int r = i >> 7, jb = i & 127;
  float acc[8] = {0.f, 0.f, 0.f, 0.f, 0.f, 0.f, 0.f, 0.f};
  for (int c = 0; c < IN_SZ; ++c) {
    float w = Wih0[r * IN_SZ + c];
    const float* f = &fcW[c * H_SZ + jb * 8];
#pragma unroll
    for (int e = 0; e < 8; ++e) acc[e] = fmaf(w, f[e], acc[e]);
  }
  unsigned short* d = dst + ((long)r * 256 + jb) * 16;
#pragma unroll
  for (int e = 0; e < 8; ++e) {
    unsigned short s0 = bf16rne(acc[e]);
    float rr = acc[e] - bf2f(s0);
    d[e] = s0;
    d[8 + e] = bf16rne(rr);
  }
}

__global__ void bias_kernel(const float* bih0, const float* bhh0,
                            const float* bih1, const float* bhh1,
                            const float* __restrict__ Wih0,
                            const float* __restrict__ fcb,
                            float* b_init, float* b0p, float* b1p) {
  int i = blockIdx.x * 256 + threadIdx.x;
  if (i < H_SZ) {
    float sum = 0.f;
    for (int c = 0; c < IN_SZ; ++c) sum += Wih0[i * IN_SZ + c] * fcb[c];
    float bi = bih0[i] + bhh0[i];
    b_init[i] = bi;
    b0p[i] = bi + sum;
    b1p[i] = bih1[i] + bhh1[i];
  }
}

__global__ void y0copy_kernel(const float* __restrict__ y0,
                              float* __restrict__ out, int T) {
  int o = blockIdx.x * 256 + threadIdx.x;
  int b = o >> 6, c = (o & 63) << 2;
  *(float4*)&out[(size_t)b * T * IN_SZ + c] = *(const float4*)&y0[b * IN_SZ + c];
}

// ============================================================================
// Fallback f32 path (round-2, passing) — only if ws too small.
// ============================================================================
#define KC 128
#define KCP 132
#define LTILES 256
#define FTILES 64
struct alignas(16) SmemT { float A[16][KCP]; float W[64][KCP]; };
struct RnnArgs {
  const float *y0, *W_ih0, *W_hh0, *W_ih1, *W_hh1, *fc_W, *fc_b;
  const float *Wc, *b_init, *b0p, *b1p;
  float *h0a, *h0b, *h1a, *h1b, *out;
  unsigned *cnt, *abortf;
  int T, nwg, mode;
};
__device__ __forceinline__ void gemm_accum(const float* __restrict__ X, int ldx,
                                           const float* __restrict__ Wm, int K,
                                           int m0, int n0, int wv, int lane, int tid,
                                           SmemT& s, float* acc) {
  for (int kc = 0; kc < K; kc += KC) {
#pragma unroll
    for (int i = 0; i < 2; ++i) {
      int a = i * 256 + tid; int r = a >> 5, k = (a & 31) << 2;
      *(float4*)&s.A[r][k] = *(const float4*)&X[(size_t)(m0 + r) * ldx + kc + k];
    }
#pragma unroll
    for (int i = 0; i < 8; ++i) {
      int a = i * 256 + tid; int c = a >> 5, k = (a & 31) << 2;
      *(float4*)&s.W[c][k] = *(const float4*)&Wm[(size_t)(n0 + c) * K + kc + k];
    }
    __syncthreads();
#pragma unroll 4
    for (int k4 = 0; k4 < KC; k4 += 4) {
      float4 w4 = *(float4*)&s.W[lane][k4];
#pragma unroll
      for (int j = 0; j < 4; ++j) {
        float4 a4 = *(float4*)&s.A[wv + 4 * j][k4];
        acc[j] = fmaf(a4.x, w4.x, acc[j]); acc[j] = fmaf(a4.y, w4.y, acc[j]);
        acc[j] = fmaf(a4.z, w4.z, acc[j]); acc[j] = fmaf(a4.w, w4.w, acc[j]);
      }
    }
    __syncthreads();
  }
}
__global__ void __launch_bounds__(256) rnn_seq_kernel(RnnArgs a) {
  __shared__ SmemT s;
  __shared__ unsigned fail_s;
  bool dead = false;
  const int wg = blockIdx.x, tid = threadIdx.x;
  const int wv = tid >> 6, lane = tid & 63;
  const int T = a.T, nwg = a.nwg, mode = a.mode;
  const int ldo = T * IN_SZ;
  const float* h0[2] = {a.h0a, a.h0b};
  const float* h1[2] = {a.h1a, a.h1b};
  float* h0w[2] = {a.h0a, a.h0b};
  float* h1w[2] = {a.h1a, a.h1b};
  int cur = 0, bar = 0;
  for (int t = 1; t < T; ++t) {
    const int nxt = cur ^ 1;
    for (int tl = wg; tl < LTILES; tl += nwg) {
      const int m0 = (tl >> 4) << 4;
      const int n0 = (((tl & 7) << 1) | ((tl >> 3) & 1)) << 6;
      float acc[4] = {0.f, 0.f, 0.f, 0.f};
      const float* bias;
      if (t == 1) { gemm_accum(a.y0, IN_SZ, a.W_ih0, IN_SZ, m0, n0, wv, lane, tid, s, acc); bias = a.b_init; }
      else if (mode == 0) { gemm_accum(h1[cur], H_SZ, a.Wc, H_SZ, m0, n0, wv, lane, tid, s, acc); bias = a.b0p; }
      else { gemm_accum(a.out + (size_t)(t - 1) * IN_SZ, ldo, a.W_ih0, IN_SZ, m0, n0, wv, lane, tid, s, acc); bias = a.b_init; }
      gemm_accum(h0[cur], H_SZ, a.W_hh0, H_SZ, m0, n0, wv, lane, tid, s, acc);
      const float bv = bias[n0 + lane];
#pragma unroll
      for (int j = 0; j < 4; ++j)
        h0w[nxt][(size_t)(m0 + wv + 4 * j) * H_SZ + n0 + lane] = tanhf(acc[j] + bv);
    }
    grid_barrier(a.cnt, bar++, (unsigned)nwg, a.abortf, &fail_s, &dead);
    for (int tl = wg; tl < LTILES; tl += nwg) {
      const int m0 = (tl >> 4) << 4;
      const int n0 = (((tl & 7) << 1) | ((tl >> 3) & 1)) << 6;
      float acc[4] = {0.f, 0.f, 0.f, 0.f};
      gemm_accum(h0[nxt], H_SZ, a.W_ih1, H_SZ, m0, n0, wv, lane, tid, s, acc);
      gemm_accum(h1[cur], H_SZ, a.W_hh1, H_SZ, m0, n0, wv, lane, tid, s, acc);
      const float bv = a.b1p[n0 + lane];
#pragma unroll
      for (int j = 0; j < 4; ++j)
        h1w[nxt][(size_t)(m0 + wv + 4 * j) * H_SZ + n0 + lane] = tanhf(acc[j] + bv);
    }
    grid_barrier(a.cnt, bar++, (unsigned)nwg, a.abortf, &fail_s, &dead);
    for (int ft = wg; ft < FTILES; ft += nwg) {
      const int m0 = (ft >> 2) << 4;
      const int n0 = (ft & 3) << 6;
      float acc[4] = {0.f, 0.f, 0.f, 0.f};
      gemm_accum(h1[nxt], H_SZ, a.fc_W, H_SZ, m0, n0, wv, lane, tid, s, acc);
      const float bv = a.fc_b[n0 + lane];
#pragma unroll
      for (int j = 0; j < 4; ++j)
        a.out[(size_t)(m0 + wv + 4 * j) * ldo + (size_t)t * IN_SZ + n0 + lane] = acc[j] + bv;
    }
    if (mode == 1)
      grid_barrier(a.cnt, bar++, (unsigned)nwg, a.abortf, &fail_s, &dead);
    cur = nxt;
  }
}
__global__ void __launch_bounds__(256) wc_kernel(const float* __restrict__ Wih0,
                                                 const float* __restrict__ fcW,
                                                 float* __restrict__ Wc) {
  int o = blockIdx.x * 256 + threadIdx.x;
  int i = o >> 8, j0 = (o & 255) << 2;
  float4 acc = {0.f, 0.f, 0.f, 0.f};
  for (int c = 0; c < IN_SZ; ++c) {
    float a = Wih0[i * IN_SZ + c];
    float4 f = *(const float4*)&fcW[c * H_SZ + j0];
    acc.x += a * f.x; acc.y += a * f.y; acc.z += a * f.z; acc.w += a * f.w;
  }
  *(float4*)&Wc[(size_t)i * H_SZ + j0] = acc;
}

// ============================================================================
extern "C" void kernel_launch(void* const* d_in, const int* in_sizes, int n_in,
                              void* d_out, int out_size, void* d_ws, size_t ws_size,
                              hipStream_t stream) {
  const float* y0    = (const float*)d_in[0];
  const float* W_ih0 = (const float*)d_in[2];
  const float* W_hh0 = (const float*)d_in[3];
  const float* b_ih0 = (const float*)d_in[4];
  const float* b_hh0 = (const float*)d_in[5];
  const float* W_ih1 = (const float*)d_in[6];
  const float* W_hh1 = (const float*)d_in[7];
  const float* b_ih1 = (const float*)d_in[8];
  const float* b_hh1 = (const float*)d_in[9];
  const float* fc_W  = (const float*)d_in[10];
  const float* fc_b  = (const float*)d_in[11];
  const int T = in_sizes[1];   // 512

  // ---- MFMA-path workspace (shorts, then floats) ----
  const long B0N = 1024L * 256 * 16;   // 4,194,304 shorts (pack2, KBtot=256)
  const long B1N = B0N;
  const long W0N = 1024L * 32 * 16;    // 524,288
  const long FCN = 256L * 128 * 16;    // 524,288
  const long hN  = (long)B_SZ * H_SZ;  // 262,144 floats per buffer
  const size_t needNew = (2 * B0N + W0N + FCN) * 2 +
                         (4 * hN + 3 * H_SZ) * 4 + (2L * T + 8) * 4;

  if (ws_size >= needNew) {
    unsigned short* ws16 = (unsigned short*)d_ws;
    unsigned short* B0p = ws16;  ws16 += B0N;
    unsigned short* B1p = ws16;  ws16 += B1N;
    unsigned short* W0p = ws16;  ws16 += W0N;
    unsigned short* fcp = ws16;  ws16 += FCN;
    float* wf  = (float*)ws16;
    float* h0a = wf;  wf += hN;
    float* h0b = wf;  wf += hN;
    float* h1a = wf;  wf += hN;
    float* h1b = wf;  wf += hN;
    float* b_init = wf;  wf += H_SZ;
    float* b0p = wf;     wf += H_SZ;
    float* b1p = wf;     wf += H_SZ;
    unsigned* cnt = (unsigned*)wf;
    unsigned* abortf = cnt + 2 * (size_t)T + 4;

    hipMemsetAsync(cnt, 0, (2 * (size_t)T + 5) * 4, stream);
    hipMemsetAsync(h0a, 0, hN * 4, stream);
    hipMemsetAsync(h1a, 0, hN * 4, stream);

    wc_pack2_kernel<<<512, 256, 0, stream>>>(W_ih0, fc_W, B0p);
    pack2_kernel<<<512, 256, 0, stream>>>(W_hh0, 1024, 128, B0p, 256, 128);
    pack2_kernel<<<512, 256, 0, stream>>>(W_ih1, 1024, 128, B1p, 256, 0);
    pack2_kernel<<<512, 256, 0, stream>>>(W_hh1, 1024, 128, B1p, 256, 128);
    pack2_kernel<<<128, 256, 0, stream>>>(W_ih0, 1024, 32, W0p, 32, 0);
    pack2_kernel<<<128, 256, 0, stream>>>(fc_W, 256, 128, fcp, 128, 0);
    bias_kernel<<<4, 256, 0, stream>>>(b_ih0, b_hh0, b_ih1, b_hh1, W_ih0, fc_b,
                                       b_init, b0p, b1p);
    y0copy_kernel<<<(B_SZ * IN_SZ / 4) / 256, 256, 0, stream>>>(y0, (float*)d_out, T);

    MArgs a;
    a.y0 = y0;
    a.B0p = B0p; a.B1p = B1p; a.W0p = W0p; a.fcp = fcp;
    a.h0a = h0a; a.h0b = h0b; a.h1a = h1a; a.h1b = h1b;
    a.b_init = b_init; a.b0p = b0p; a.b1p = b1p; a.fc_b = fc_b;
    a.out = (float*)d_out; a.cnt = cnt; a.abortf = abortf;
    a.T = T; a.nwg = NWG_M;
    void* kargs[] = {(void*)&a};
    hipLaunchCooperativeKernel(rnn_mfma_kernel, dim3(NWG_M), dim3(256), kargs, 0, stream);
    return;
  }

  // ---------------- fallback f32 path ----------------
  const size_t hNf = (size_t)B_SZ * H_SZ;
  const size_t wcN = (size_t)H_SZ * H_SZ;
  const size_t cntN = 3 * (size_t)T + 8;
  const size_t need_full = (wcN + 4 * hNf + 3 * H_SZ + cntN) * 4;
  const int mode = (ws_size >= need_full) ? 0 : 1;

  float* ws = (float*)d_ws;
  float* Wc = nullptr;
  if (mode == 0) { Wc = ws; ws += wcN; }
  float* h0a = ws;  ws += hNf;
  float* h0b = ws;  ws += hNf;
  float* h1a = ws;  ws += hNf;
  float* h1b = ws;  ws += hNf;
  float* b_init = ws; ws += H_SZ;
  float* b0p = ws;  ws += H_SZ;
  float* b1p = ws;  ws += H_SZ;
  unsigned* cnt = (unsigned*)ws;
  unsigned* abortf = cnt + 3 * (size_t)T;

  hipMemsetAsync(cnt, 0, cntN * sizeof(unsigned), stream);
  hipMemsetAsync(h0a, 0, hNf * sizeof(float), stream);
  hipMemsetAsync(h1a, 0, hNf * sizeof(float), stream);
  if (mode == 0)
    wc_kernel<<<(H_SZ * H_SZ / 4) / 256, 256, 0, stream>>>(W_ih0, fc_W, Wc);
  bias_kernel<<<4, 256, 0, stream>>>(b_ih0, b_hh0, b_ih1, b_hh1, W_ih0, fc_b,
                                     b_init, b0p, b1p);
  y0copy_kernel<<<(B_SZ * IN_SZ / 4) / 256, 256, 0, stream>>>(y0, (float*)d_out, T);

  RnnArgs a;
  a.y0 = y0; a.W_ih0 = W_ih0; a.W_hh0 = W_hh0; a.W_ih1 = W_ih1; a.W_hh1 = W_hh1;
  a.fc_W = fc_W; a.fc_b = fc_b;
  a.Wc = Wc; a.b_init = b_init; a.b0p = b0p; a.b1p = b1p;
  a.h0a = h0a; a.h0b = h0b; a.h1a = h1a; a.h1b = h1b;
  a.out = (float*)d_out; a.cnt = cnt; a.abortf = abortf;
  a.T = T; a.nwg = 256; a.mode = mode;
  void* kargs[] = {(void*)&a};
  hipError_t err = hipLaunchCooperativeKernel(rnn_seq_kernel, dim3(256), dim3(256),
                                              kargs, 0, stream);
  int nwg = 256;
  while (err != hipSuccess && nwg > 16) {
    nwg >>= 1; a.nwg = nwg;
    err = hipLaunchCooperativeKernel(rnn_seq_kernel, dim3(nwg), dim3(256),
                                     kargs, 0, stream);
  }
}